// Round 10
// baseline (464.987 us; speedup 1.0000x reference)
//
#include <hip/hip_runtime.h>
#include <hip/hip_bf16.h>

#define N_IN   200000
#define N_OUT  100000
#define NEDGE  1600000
#define CIN    64
#define KS     9
#define C_A    96
#define C_B    32
#define C_TOT  128
#define EPSV   1e-8f

#define TROWS  32            // output rows per block (2x MFMA M tiles)
#define RPW    4             // rows per wave
#define SHSTRIDE 584         // ushorts per LDS bin row: 576 + 8 pad
#define KSTEPS 18            // 576 / 32
#define WPACK_ELEMS (8 * KSTEPS * 64 * 8)        // 73728 bf16

// workspace layout (bytes)
#define WS_ROWBYTES 400128                        // (N_OUT+1)*4 rounded up
#define WS_WPBYTES  147456                        // WPACK_ELEMS*2
#define WS_PERMBYTES (NEDGE * 8)                  // 12.8 MB
#define WS_FB_OFF   (WS_ROWBYTES + WS_WPBYTES + WS_PERMBYTES)

#define BR_BLOCKS   ((NEDGE + 255) / 256)         // 6250: build_rows part
#define CAST_BLOCKS (N_IN * CIN / (256 * 8))      // 6250: feats->bf16 part
#define PREP_SORT_BLOCKS ((N_OUT + 3) / 4)        // 4 waves (rows) per 256-thr block
#define PACKW_BLOCKS ((WPACK_ELEMS + 255) / 256)  // 288

typedef __attribute__((ext_vector_type(8))) short short8;
typedef __attribute__((ext_vector_type(4))) float f32x4;

__device__ __forceinline__ unsigned short f2bf(float f) {
    __hip_bfloat16 h = __float2bfloat16(f);
    return __builtin_bit_cast(unsigned short, h);
}

// kernelA: blocks [0,BR_BLOCKS): CSR row offsets. blocks [BR_BLOCKS,...): feats->bf16.
__global__ void kernelA(const int* __restrict__ oidx, int* __restrict__ row,
                        const float* __restrict__ feats, unsigned short* __restrict__ fb) {
    if (blockIdx.x < BR_BLOCKS) {
        int e = blockIdx.x * 256 + threadIdx.x;
        if (e >= NEDGE) return;
        int cur  = oidx[e];
        int prev = (e == 0) ? -1 : oidx[e - 1];
        for (int o = prev + 1; o <= cur; ++o) row[o] = e;
        if (e == NEDGE - 1)
            for (int o = cur + 1; o <= N_OUT; ++o) row[o] = NEDGE;
    } else {
        int f = (blockIdx.x - BR_BLOCKS) * 256 + threadIdx.x;   // < 1.6M
        const float4* fp = reinterpret_cast<const float4*>(feats);
        float4 a = fp[f * 2];
        float4 b = fp[f * 2 + 1];
        short8 s;
        s[0] = (short)f2bf(a.x); s[1] = (short)f2bf(a.y);
        s[2] = (short)f2bf(a.z); s[3] = (short)f2bf(a.w);
        s[4] = (short)f2bf(b.x); s[5] = (short)f2bf(b.y);
        s[6] = (short)f2bf(b.z); s[7] = (short)f2bf(b.w);
        *reinterpret_cast<short8*>(fb + f * 8) = s;
    }
}

// prep: blocks [0,PREP_SORT_BLOCKS): one-wave-per-row ballot counting-sort by k.
// Emits perm2[e] = { nbr(18b) | k<<18 | (row&31)<<22 , bits(importance[nbr]) }.
// blocks [PREP_SORT_BLOCKS,...): pack W into MFMA B-frag order.
__global__ void prep_kernel(const int* __restrict__ nbr_idx,
                            const int* __restrict__ k_idx,
                            const int* __restrict__ row_start,
                            const float* __restrict__ importance,
                            const float* __restrict__ Wa,
                            const float* __restrict__ Wb,
                            uint2* __restrict__ perm2,
                            __hip_bfloat16* __restrict__ Wp) {
    if (blockIdx.x < PREP_SORT_BLOCKS) {
        const int wave = threadIdx.x >> 6;
        const int lane = threadIdx.x & 63;
        const int o = blockIdx.x * 4 + wave;
        if (o >= N_OUT) return;
        const int e0 = row_start[o];
        const int e1 = row_start[o + 1];
        if (e0 >= e1) return;
        const unsigned hi = ((unsigned)(o & 31)) << 22;
        const unsigned long long lt = (1ULL << lane) - 1ULL;

        int basek[KS];
        #pragma unroll
        for (int j = 0; j < KS; ++j) basek[j] = 0;
        for (int base = e0; base < e1; base += 64) {
            int idx = base + lane;
            int k = (idx < e1) ? k_idx[idx] : KS;
            #pragma unroll
            for (int j = 0; j < KS; ++j)
                basek[j] += (int)__popcll(__ballot(k == j));
        }
        int run = 0;
        #pragma unroll
        for (int j = 0; j < KS; ++j) { int c = basek[j]; basek[j] = run; run += c; }
        for (int base = e0; base < e1; base += 64) {
            int idx = base + lane;
            bool valid = idx < e1;
            int k = valid ? k_idx[idx] : KS;
            unsigned nb = valid ? (unsigned)nbr_idx[idx] : 0u;
            float im = importance[nb];
            int pos = 0;
            #pragma unroll
            for (int j = 0; j < KS; ++j) {
                unsigned long long mk = __ballot(k == j);
                if (k == j) pos = basek[j] + (int)__popcll(mk & lt);
                basek[j] += (int)__popcll(mk);
            }
            if (valid) {
                uint2 v;
                v.x = nb | hi | ((unsigned)k << 18);
                v.y = __builtin_bit_cast(unsigned, im);
                perm2[e0 + pos] = v;
            }
        }
    } else {
        int f = (blockIdx.x - PREP_SORT_BLOCKS) * 256 + threadIdx.x;
        if (f >= WPACK_ELEMS) return;
        int j = f & 7;
        int l = (f >> 3) & 63;
        int s = (f >> 9) % KSTEPS;
        int n = f / (512 * KSTEPS);
        int kc   = s * 32 + (l >> 4) * 8 + j;
        int cout = n * 16 + (l & 15);
        float v = (cout < C_A) ? Wa[kc * C_A + cout] : Wb[kc * C_B + (cout - C_A)];
        Wp[f] = __float2bfloat16(v);
    }
}

// V=0: Phase 1 only (asm keepalive). V=1: Phase 2 only (zero bins). V=2: full.
template<int V>
__global__ __launch_bounds__(512, 4)
void fused_kernel(const unsigned short* __restrict__ fb,
                  const float* __restrict__ b_a,
                  const float* __restrict__ b_b,
                  const uint2* __restrict__ perm2,
                  const int* __restrict__ row_start,
                  const __hip_bfloat16* __restrict__ Wp,
                  float* __restrict__ out) {
    __shared__ __align__(16) unsigned short binh_a[TROWS][SHSTRIDE];
    __shared__ __align__(16) unsigned short binh_b[TROWS][SHSTRIDE];
    __shared__ uint2 stage[8][64];     // per-wave 64-edge metadata staging
    __shared__ float imp_s[TROWS];

    const int tid  = threadIdx.x;
    const int wave = tid >> 6;
    const int lane = tid & 63;
    const int o0   = blockIdx.x * TROWS;

    // zero bins + imp
    {
        uint4 z = {0u, 0u, 0u, 0u};
        uint4* pa = reinterpret_cast<uint4*>(&binh_a[0][0]);
        uint4* pb = reinterpret_cast<uint4*>(&binh_b[0][0]);
        const int n16 = TROWS * SHSTRIDE / 8;   // 2336
        for (int idx = tid; idx < n16; idx += 512) { pa[idx] = z; pb[idx] = z; }
        if (tid < TROWS) imp_s[tid] = 0.f;
    }
    __syncthreads();

    // ---- Phase 1: wave w streams the merged edge range of rows [o0+4w, o0+4w+4).
    // tag = x>>18 = (lrow<<4)|k; tag-change flush covers k- and row-boundaries.
    if constexpr (V != 1) {
        const int r0 = o0 + wave * RPW;
        const int E0 = __builtin_amdgcn_readfirstlane(row_start[r0]);
        const int E4 = __builtin_amdgcn_readfirstlane(row_start[r0 + RPW]);

        if (E0 < E4) {
            int tagc = __builtin_amdgcn_readfirstlane((int)(perm2[E0].x >> 18));
            float acc_a = 0.f, acc_b = 0.f, isum = 0.f;

            for (int p = E0; p < E4; p += 64) {
                const int c = E4 - p;                 // wave-uniform remaining
                int q = p + lane; if (q >= E4) q = E4 - 1;
                stage[wave][lane] = perm2[q];         // coalesced dwordx2 + ds_write

                for (int sb = 0; sb < 8; ++sb) {
                    if (sb * 8 >= c) break;           // wave-uniform
                    uint2 e[8]; unsigned short gh[8];
                    #pragma unroll
                    for (int j = 0; j < 8; ++j)
                        e[j] = stage[wave][sb * 8 + j];   // uniform -> broadcast
                    #pragma unroll
                    for (int j = 0; j < 8; ++j)
                        gh[j] = fb[(e[j].x & 0x3FFFFu) * CIN + lane];  // 128B coalesced
                    #pragma unroll
                    for (int j = 0; j < 8; ++j)
                        asm volatile("" : "+v"(gh[j]));
                    __builtin_amdgcn_sched_barrier(0);
                    #pragma unroll
                    for (int j = 0; j < 8; ++j) {
                        if (sb * 8 + j < c) {             // wave-uniform
                            const int tag = __builtin_amdgcn_readfirstlane((int)(e[j].x >> 18));
                            if (tag != tagc) {
                                binh_a[tagc >> 4][(tagc & 15) * CIN + lane] = f2bf(acc_a);
                                binh_b[tagc >> 4][(tagc & 15) * CIN + lane] = f2bf(acc_b);
                                acc_a = 0.f; acc_b = 0.f;
                                if ((tag >> 4) != (tagc >> 4)) {
                                    if (lane == 0) imp_s[tagc >> 4] = isum;
                                    isum = 0.f;
                                }
                                tagc = tag;
                            }
                            const float iv = __builtin_bit_cast(float, e[j].y);
                            const float g = __builtin_bit_cast(float, (unsigned)gh[j] << 16);
                            acc_a += g;
                            acc_b = fmaf(g, iv, acc_b);
                            isum += iv;
                        }
                    }
                }
            }
            binh_a[tagc >> 4][(tagc & 15) * CIN + lane] = f2bf(acc_a);
            binh_b[tagc >> 4][(tagc & 15) * CIN + lane] = f2bf(acc_b);
            if (lane == 0) imp_s[tagc >> 4] = isum;
        }
    }
    __syncthreads();

    if constexpr (V == 0) {
        // keep Phase 1 live without Phase 2 (rule: asm-use, runtime-indexed reads)
        float chk = (float)binh_a[tid & 31][(tid * 37) & 511]
                  + (float)binh_b[tid & 31][(tid * 53) & 511]
                  + imp_s[tid & 31];
        asm volatile("" :: "v"(chk));
        return;
    } else {
        // ---- Phase 2: wave w owns cout tile w (16 couts), both 16-row halves.
        // Waves 0-5 contract binh_a (C_A=96), waves 6-7 binh_b (C_B=32).
        const unsigned short* binp = (wave < 6) ? &binh_a[0][0] : &binh_b[0][0];
        const int mrow = lane & 15;
        const int kgrp = lane >> 4;
        f32x4 acc0 = {0.f, 0.f, 0.f, 0.f};
        f32x4 acc1 = {0.f, 0.f, 0.f, 0.f};
        const short8* wp = reinterpret_cast<const short8*>(Wp) + wave * KSTEPS * 64 + lane;
        const unsigned short* ap0 = binp + mrow * SHSTRIDE + kgrp * 8;
        #pragma unroll
        for (int s = 0; s < KSTEPS; ++s) {
            short8 b = wp[s * 64];                    // shared across both M halves
            short8 a0 = *reinterpret_cast<const short8*>(ap0 + s * 32);
            short8 a1 = *reinterpret_cast<const short8*>(ap0 + 16 * SHSTRIDE + s * 32);
            acc0 = __builtin_amdgcn_mfma_f32_16x16x32_bf16(a0, b, acc0, 0, 0, 0);
            acc1 = __builtin_amdgcn_mfma_f32_16x16x32_bf16(a1, b, acc1, 0, 0, 0);
        }

        int cout = wave * 16 + mrow;
        float bias = (wave < 6) ? b_a[cout] : b_b[cout - C_A];
        #pragma unroll
        for (int j = 0; j < 4; ++j) {
            int t = kgrp * 4 + j;
            float y = acc0[j];
            if (wave >= 6) y = y / fmaxf(imp_s[t], EPSV);
            y += bias; y = fmaxf(y, 0.f);
            out[(long)(o0 + t) * C_TOT + cout] = y;
        }
        #pragma unroll
        for (int j = 0; j < 4; ++j) {
            int t = 16 + kgrp * 4 + j;
            float y = acc1[j];
            if (wave >= 6) y = y / fmaxf(imp_s[t], EPSV);
            y += bias; y = fmaxf(y, 0.f);
            out[(long)(o0 + t) * C_TOT + cout] = y;
        }
        if (wave == 7 && lane < TROWS)
            out[(long)N_OUT * C_TOT + o0 + lane] = imp_s[lane];
    }
}

extern "C" void kernel_launch(void* const* d_in, const int* in_sizes, int n_in,
                              void* d_out, int out_size, void* d_ws, size_t ws_size,
                              hipStream_t stream) {
    const float* feats      = (const float*)d_in[0];
    const float* importance = (const float*)d_in[1];
    const float* W_a        = (const float*)d_in[2];
    const float* b_a        = (const float*)d_in[3];
    const float* W_b        = (const float*)d_in[4];
    const float* b_b        = (const float*)d_in[5];
    const int*   nbr        = (const int*)d_in[6];
    const int*   kidx       = (const int*)d_in[7];
    const int*   oidx       = (const int*)d_in[8];
    float* out = (float*)d_out;

    int* row_start = (int*)d_ws;
    __hip_bfloat16* Wp = (__hip_bfloat16*)((char*)d_ws + WS_ROWBYTES);
    uint2* perm2 = (uint2*)((char*)d_ws + WS_ROWBYTES + WS_WPBYTES);
    unsigned short* fb = (unsigned short*)((char*)d_ws + WS_FB_OFF);

    hipLaunchKernelGGL(kernelA, dim3(BR_BLOCKS + CAST_BLOCKS), dim3(256), 0, stream,
                       oidx, row_start, feats, fb);
    hipLaunchKernelGGL(prep_kernel, dim3(PREP_SORT_BLOCKS + PACKW_BLOCKS), dim3(256), 0, stream,
                       nbr, kidx, row_start, importance, W_a, W_b, perm2, Wp);
    // Ablation (this round only): V0 = Phase1-only, V1 = Phase2-only, V2 = full (last, real out).
    hipLaunchKernelGGL((fused_kernel<0>), dim3(N_OUT / TROWS), dim3(512), 0, stream,
                       fb, b_a, b_b, perm2, row_start, Wp, out);
    hipLaunchKernelGGL((fused_kernel<1>), dim3(N_OUT / TROWS), dim3(512), 0, stream,
                       fb, b_a, b_b, perm2, row_start, Wp, out);
    hipLaunchKernelGGL((fused_kernel<2>), dim3(N_OUT / TROWS), dim3(512), 0, stream,
                       fb, b_a, b_b, perm2, row_start, Wp, out);
}

// Round 11
// 232.694 us; speedup vs baseline: 1.9983x; 1.9983x over previous
//
#include <hip/hip_runtime.h>
#include <hip/hip_bf16.h>

#define N_IN   200000
#define N_OUT  100000
#define NEDGE  1600000
#define CIN    64
#define KS     9
#define C_A    96
#define C_B    32
#define C_TOT  128
#define EPSV   1e-8f

#define TROWS  16            // output rows per block (MFMA M)
#define SHSTRIDE 584         // ushorts per LDS bin row: 576 + 8 pad (16B multiple)
#define KSTEPS 18            // 576 / 32
#define WPACK_ELEMS (8 * KSTEPS * 64 * 8)        // 73728 bf16

// workspace layout (bytes)
#define WS_ROWBYTES 400128                        // (N_OUT+1)*4 rounded up
#define WS_WPBYTES  147456                        // WPACK_ELEMS*2
#define WS_PERMBYTES (NEDGE * 8)                  // 12.8 MB
#define WS_FB_OFF   (WS_ROWBYTES + WS_WPBYTES + WS_PERMBYTES)

#define BR_BLOCKS   ((NEDGE + 255) / 256)         // 6250: build_rows part
#define CAST_BLOCKS (N_IN * CIN / (256 * 8))      // 6250: feats->bf16 part
#define PREP_SORT_BLOCKS ((N_OUT + 3) / 4)        // 4 waves (rows) per 256-thr block
#define PACKW_BLOCKS ((WPACK_ELEMS + 255) / 256)  // 288

typedef __attribute__((ext_vector_type(8))) short short8;
typedef __attribute__((ext_vector_type(4))) float f32x4;

__device__ __forceinline__ unsigned short f2bf(float f) {
    __hip_bfloat16 h = __float2bfloat16(f);
    return __builtin_bit_cast(unsigned short, h);
}

// kernelA: blocks [0,BR_BLOCKS): CSR row offsets. blocks [BR_BLOCKS,...): feats->bf16.
__global__ void kernelA(const int* __restrict__ oidx, int* __restrict__ row,
                        const float* __restrict__ feats, unsigned short* __restrict__ fb) {
    if (blockIdx.x < BR_BLOCKS) {
        int e = blockIdx.x * 256 + threadIdx.x;
        if (e >= NEDGE) return;
        int cur  = oidx[e];
        int prev = (e == 0) ? -1 : oidx[e - 1];
        for (int o = prev + 1; o <= cur; ++o) row[o] = e;
        if (e == NEDGE - 1)
            for (int o = cur + 1; o <= N_OUT; ++o) row[o] = NEDGE;
    } else {
        int f = (blockIdx.x - BR_BLOCKS) * 256 + threadIdx.x;   // < 1.6M
        const float4* fp = reinterpret_cast<const float4*>(feats);
        float4 a = fp[f * 2];
        float4 b = fp[f * 2 + 1];
        short8 s;
        s[0] = (short)f2bf(a.x); s[1] = (short)f2bf(a.y);
        s[2] = (short)f2bf(a.z); s[3] = (short)f2bf(a.w);
        s[4] = (short)f2bf(b.x); s[5] = (short)f2bf(b.y);
        s[6] = (short)f2bf(b.z); s[7] = (short)f2bf(b.w);
        *reinterpret_cast<short8*>(fb + f * 8) = s;
    }
}

// prep: blocks [0,PREP_SORT_BLOCKS): one-wave-per-row ballot counting-sort by k.
// Emits perm2[e] = { nbr(18b) | k<<18 | (row&15)<<22 , bits(importance[nbr]) }.
// blocks [PREP_SORT_BLOCKS,...): pack W into MFMA B-frag order.
__global__ void prep_kernel(const int* __restrict__ nbr_idx,
                            const int* __restrict__ k_idx,
                            const int* __restrict__ row_start,
                            const float* __restrict__ importance,
                            const float* __restrict__ Wa,
                            const float* __restrict__ Wb,
                            uint2* __restrict__ perm2,
                            __hip_bfloat16* __restrict__ Wp) {
    if (blockIdx.x < PREP_SORT_BLOCKS) {
        const int wave = threadIdx.x >> 6;
        const int lane = threadIdx.x & 63;
        const int o = blockIdx.x * 4 + wave;
        if (o >= N_OUT) return;
        const int e0 = row_start[o];
        const int e1 = row_start[o + 1];
        if (e0 >= e1) return;
        const unsigned hi = ((unsigned)(o & 15)) << 22;
        const unsigned long long lt = (1ULL << lane) - 1ULL;

        int basek[KS];
        #pragma unroll
        for (int j = 0; j < KS; ++j) basek[j] = 0;
        for (int base = e0; base < e1; base += 64) {
            int idx = base + lane;
            int k = (idx < e1) ? k_idx[idx] : KS;
            #pragma unroll
            for (int j = 0; j < KS; ++j)
                basek[j] += (int)__popcll(__ballot(k == j));
        }
        int run = 0;
        #pragma unroll
        for (int j = 0; j < KS; ++j) { int c = basek[j]; basek[j] = run; run += c; }
        for (int base = e0; base < e1; base += 64) {
            int idx = base + lane;
            bool valid = idx < e1;
            int k = valid ? k_idx[idx] : KS;
            unsigned nb = valid ? (unsigned)nbr_idx[idx] : 0u;
            float im = importance[nb];
            int pos = 0;
            #pragma unroll
            for (int j = 0; j < KS; ++j) {
                unsigned long long mk = __ballot(k == j);
                if (k == j) pos = basek[j] + (int)__popcll(mk & lt);
                basek[j] += (int)__popcll(mk);
            }
            if (valid) {
                uint2 v;
                v.x = nb | hi | ((unsigned)k << 18);
                v.y = __builtin_bit_cast(unsigned, im);
                perm2[e0 + pos] = v;
            }
        }
    } else {
        int f = (blockIdx.x - PREP_SORT_BLOCKS) * 256 + threadIdx.x;
        if (f >= WPACK_ELEMS) return;
        int j = f & 7;
        int l = (f >> 3) & 63;
        int s = (f >> 9) % KSTEPS;
        int n = f / (512 * KSTEPS);
        int kc   = s * 32 + (l >> 4) * 8 + j;
        int cout = n * 16 + (l & 15);
        float v = (cout < C_A) ? Wa[kc * C_A + cout] : Wb[kc * C_B + (cout - C_A)];
        Wp[f] = __float2bfloat16(v);
    }
}

// LDS budget: bins 2*16*584*2 = 37376 B + stage 2048 B + imp 64 B = 39488 B
// (< 40 KB => 4 blocks/CU = 32 waves/CU). R9->R10 A/B showed Phase-1 throughput
// scales with resident waves; this is the occupancy-maximizing configuration.
__global__ __launch_bounds__(512, 8)
void fused_kernel(const unsigned short* __restrict__ fb,
                  const float* __restrict__ b_a,
                  const float* __restrict__ b_b,
                  const uint2* __restrict__ perm2,
                  const int* __restrict__ row_start,
                  const __hip_bfloat16* __restrict__ Wp,
                  float* __restrict__ out) {
    __shared__ __align__(16) unsigned short binh_a[TROWS][SHSTRIDE];
    __shared__ __align__(16) unsigned short binh_b[TROWS][SHSTRIDE];
    __shared__ uint2 stage[8][32];     // per-wave 32-edge metadata staging
    __shared__ float imp_s[TROWS];

    const int tid  = threadIdx.x;
    const int wave = tid >> 6;
    const int lane = tid & 63;
    const int o0   = blockIdx.x * TROWS;

    // zero bins (16B stores)
    {
        uint4 z = {0u, 0u, 0u, 0u};
        uint4* pa = reinterpret_cast<uint4*>(&binh_a[0][0]);
        uint4* pb = reinterpret_cast<uint4*>(&binh_b[0][0]);
        #pragma unroll
        for (int i = 0; i < 3; ++i) {
            int idx = tid + i * 512;
            if (idx < TROWS * SHSTRIDE / 8) { pa[idx] = z; pb[idx] = z; }
        }
    }
    __syncthreads();

    // ---- Phase 1: wave w streams the merged edge range of rows 2w, 2w+1.
    // tag = x>>18 = (lrow<<4)|k; tag-change flush covers k- and row-boundaries.
    const int lrow0 = wave * 2;
    const int E0 = __builtin_amdgcn_readfirstlane(row_start[o0 + lrow0]);
    const int E2 = __builtin_amdgcn_readfirstlane(row_start[o0 + lrow0 + 2]);
    float isum0 = 0.f, isum1 = 0.f;

    if (E0 < E2) {
        int tagc = __builtin_amdgcn_readfirstlane((int)(perm2[E0].x >> 18));
        float acc_a = 0.f, acc_b = 0.f;

        #define FLUSH() do {                                              \
            binh_a[tagc >> 4][(tagc & 15) * CIN + lane] = f2bf(acc_a);    \
            binh_b[tagc >> 4][(tagc & 15) * CIN + lane] = f2bf(acc_b);    \
            acc_a = 0.f; acc_b = 0.f; } while (0)

        for (int p = E0; p < E2; p += 32) {
            const int c = E2 - p;                 // wave-uniform remaining count
            if (lane < 32) {
                int q = p + lane; if (q >= E2) q = E2 - 1;
                stage[wave][lane] = perm2[q];     // coalesced dwordx2 + ds_write
            }

            for (int sb = 0; sb < 4; ++sb) {
                if (sb * 8 >= c) break;           // wave-uniform
                uint2 e[8]; unsigned short gh[8];
                #pragma unroll
                for (int j = 0; j < 8; ++j)
                    e[j] = stage[wave][sb * 8 + j];   // uniform addr -> broadcast
                #pragma unroll
                for (int j = 0; j < 8; ++j)
                    gh[j] = fb[(e[j].x & 0x3FFFFu) * CIN + lane];  // 128B coalesced
                #pragma unroll
                for (int j = 0; j < 8; ++j)
                    asm volatile("" : "+v"(gh[j]));   // keep batch in flight
                __builtin_amdgcn_sched_barrier(0);
                #pragma unroll
                for (int j = 0; j < 8; ++j) {
                    if (sb * 8 + j < c) {             // wave-uniform (scalar)
                        const int tag = __builtin_amdgcn_readfirstlane((int)(e[j].x >> 18));
                        if (tag != tagc) { FLUSH(); tagc = tag; }
                        const float iv = __builtin_bit_cast(float, e[j].y);
                        const float g = __builtin_bit_cast(float, (unsigned)gh[j] << 16);
                        acc_a += g;
                        acc_b = fmaf(g, iv, acc_b);
                        if ((tag >> 4) & 1) isum1 += iv; else isum0 += iv;
                    }
                }
            }
        }
        FLUSH();
        #undef FLUSH
    }
    if (lane == 0) { imp_s[lrow0] = isum0; imp_s[lrow0 + 1] = isum1; }
    __syncthreads();

    // ---- Phase 2: wave w computes 16x16 tile (couts w*16..w*16+15).
    // Waves 0-5 contract binh_a (C_A=96), waves 6-7 binh_b (C_B=32).
    const unsigned short* binp = (wave < 6) ? &binh_a[0][0] : &binh_b[0][0];
    const int mrow = lane & 15;   // A-fragment M index
    const int kgrp = lane >> 4;   // K-chunk select
    f32x4 acc = {0.f, 0.f, 0.f, 0.f};
    const short8* wp = reinterpret_cast<const short8*>(Wp) + wave * KSTEPS * 64 + lane;
    const unsigned short* ap0 = binp + mrow * SHSTRIDE + kgrp * 8;
    #pragma unroll
    for (int s = 0; s < KSTEPS; ++s) {
        short8 a = *reinterpret_cast<const short8*>(ap0 + s * 32);  // direct bf16 frag
        short8 b = wp[s * 64];
        acc = __builtin_amdgcn_mfma_f32_16x16x32_bf16(a, b, acc, 0, 0, 0);
    }

    // Epilogue: bias + (importance norm for B path) + relu; C/D: col=lane&15, row=kgrp*4+j
    int cout = wave * 16 + mrow;
    float bias = (wave < 6) ? b_a[cout] : b_b[cout - C_A];
    #pragma unroll
    for (int j = 0; j < 4; ++j) {
        int t = kgrp * 4 + j;
        float y = acc[j];
        if (wave >= 6) y = y / fmaxf(imp_s[t], EPSV);
        y += bias;
        y = fmaxf(y, 0.f);
        out[(long)(o0 + t) * C_TOT + cout] = y;
    }
    if (wave == 7 && lane < TROWS)
        out[(long)N_OUT * C_TOT + o0 + lane] = imp_s[lane];
}

extern "C" void kernel_launch(void* const* d_in, const int* in_sizes, int n_in,
                              void* d_out, int out_size, void* d_ws, size_t ws_size,
                              hipStream_t stream) {
    const float* feats      = (const float*)d_in[0];
    const float* importance = (const float*)d_in[1];
    const float* W_a        = (const float*)d_in[2];
    const float* b_a        = (const float*)d_in[3];
    const float* W_b        = (const float*)d_in[4];
    const float* b_b        = (const float*)d_in[5];
    const int*   nbr        = (const int*)d_in[6];
    const int*   kidx       = (const int*)d_in[7];
    const int*   oidx       = (const int*)d_in[8];
    float* out = (float*)d_out;

    int* row_start = (int*)d_ws;
    __hip_bfloat16* Wp = (__hip_bfloat16*)((char*)d_ws + WS_ROWBYTES);
    uint2* perm2 = (uint2*)((char*)d_ws + WS_ROWBYTES + WS_WPBYTES);
    unsigned short* fb = (unsigned short*)((char*)d_ws + WS_FB_OFF);

    hipLaunchKernelGGL(kernelA, dim3(BR_BLOCKS + CAST_BLOCKS), dim3(256), 0, stream,
                       oidx, row_start, feats, fb);
    hipLaunchKernelGGL(prep_kernel, dim3(PREP_SORT_BLOCKS + PACKW_BLOCKS), dim3(256), 0, stream,
                       nbr, kidx, row_start, importance, W_a, W_b, perm2, Wp);
    hipLaunchKernelGGL(fused_kernel, dim3(N_OUT / TROWS), dim3(512), 0, stream,
                       fb, b_a, b_b, perm2, row_start, Wp, out);
}